// Round 1
// baseline (124.450 us; speedup 1.0000x reference)
//
#include <hip/hip_runtime.h>

#define NCELLS (8192 * 7 * 7)   // 401408 cells of 30 floats each
#define BLOCK 256
#define GRID 512                // 2 blocks/CU on 256 CUs, balanced; grid-stride over cells
                                // -> only 512*3 = 1536 same-line atomics (R1 survived 4704)

__device__ __forceinline__ float sq(float x) { return x * x; }

__device__ __forceinline__ float iou_fn(const float* t, const float* p, float fi, float fj) {
    const float STEP = 1.0f / 7.0f;
    float w1 = t[2], h1 = t[3];
    float x1 = (t[0] + fj) * STEP, y1 = (t[1] + fi) * STEP;
    float a1 = fmaxf(x1 - w1 * 0.5f, 0.0f);
    float b1 = fmaxf(y1 - h1 * 0.5f, 0.0f);
    float w2 = p[2], h2 = p[3];
    float x2 = (p[0] + fj) * STEP, y2 = (p[1] + fi) * STEP;
    float a2 = fmaxf(x2 - w2 * 0.5f, 0.0f);
    float b2 = fmaxf(y2 - h2 * 0.5f, 0.0f);
    float iw = w1 + w2 - (fmaxf(a1 + w1, a2 + w2) - fminf(a1, a2));
    float ih = h1 + h2 - (fmaxf(b1 + h1, b2 + h2) - fminf(b1, b2));
    bool valid = (iw > 0.0f) && (ih > 0.0f);
    float inter = valid ? iw * ih : 0.0f;
    float uni = w1 * h1 + w2 * h2 - inter;
    return valid ? inter / uni : 0.0f;
}

// Single fused kernel. NO d_ws use at all: the 256 MiB workspace re-poison fill
// (41 us each in rocprof, dominating the 114 us) should leave the timed window.
// d_out is zeroed by a 12-byte memset before launch; each block contributes its
// partial via 3 device-scope atomicAdds.
__global__ __launch_bounds__(BLOCK) void yolo_fused_kernel(
        const float* __restrict__ pred, const float* __restrict__ target,
        float* __restrict__ out) {
    float conf = 0.0f, reg = 0.0f, cls = 0.0f;

    for (int c = blockIdx.x * BLOCK + threadIdx.x; c < NCELLS; c += GRID * BLOCK) {
        unsigned cell = (unsigned)c % 49u;
        float fi = (float)(cell / 7u);
        float fj = (float)(cell % 7u);

        const float* p = pred + (size_t)c * 30;
        const float* t = target + (size_t)c * 30;

        float pl[30], tl[30];
#pragma unroll
        for (int k = 0; k < 15; ++k) {          // cells are 8B-aligned -> float2 OK
            float2 pv = ((const float2*)p)[k];
            float2 tv = ((const float2*)t)[k];
            pl[2 * k] = pv.x; pl[2 * k + 1] = pv.y;
            tl[2 * k] = tv.x; tl[2 * k + 1] = tv.y;
        }

        bool obj = tl[4] > 0.0f;                // target[...,4] is exactly 1.0 or 0.0

        float iou1 = iou_fn(tl, pl, fi, fj);
        float iou2 = iou_fn(tl, pl + 5, fi, fj);
        bool choose1 = iou1 > iou2;
        float m1 = (obj && choose1 && (iou1 != 0.0f)) ? 1.0f : 0.0f;
        float m2 = (obj && !choose1 && (iou2 != 0.0f)) ? 1.0f : 0.0f;

        float obj_loss = m1 * sq(iou1 - pl[4]) + m2 * sq(iou2 - pl[9]);

        float xy = m1 * (sq(tl[0] - pl[0]) + sq(tl[1] - pl[1]))
                 + m2 * (sq(tl[5] - pl[5]) + sq(tl[6] - pl[6]));

        float wh = m1 * (sq(sqrtf(tl[2]) - sqrtf(pl[2])) + sq(sqrtf(tl[3]) - sqrtf(pl[3])))
                 + m2 * (sq(sqrtf(tl[7]) - sqrtf(pl[7])) + sq(sqrtf(tl[8]) - sqrtf(pl[8])));

        float noobj = 0.0f;
#pragma unroll
        for (int k = 0; k < 6; ++k) {
            int ci = 4 + 5 * k;                 // 4, 9, 14, 19, 24, 29
            noobj += sq(tl[ci] - pl[ci]);
        }
        if (obj) noobj = 0.0f;

        float clsum = 0.0f;
#pragma unroll
        for (int k = 10; k < 30; ++k) clsum += sq(pl[k] - tl[k]);
        if (!obj) clsum = 0.0f;

        conf += obj_loss + 0.5f * noobj;
        reg  += xy + wh;
        cls  += clsum;
    }

#pragma unroll
    for (int off = 32; off > 0; off >>= 1) {
        conf += __shfl_down(conf, off, 64);
        reg  += __shfl_down(reg,  off, 64);
        cls  += __shfl_down(cls,  off, 64);
    }

    __shared__ float s[3][4];
    int lane = threadIdx.x & 63;
    int wave = threadIdx.x >> 6;
    if (lane == 0) { s[0][wave] = conf; s[1][wave] = reg; s[2][wave] = cls; }
    __syncthreads();
    if (threadIdx.x == 0) {
        const float invB = 1.0f / 8192.0f;      // scale once per block (sum-then-divide, like ref)
        atomicAdd(&out[0], (s[0][0] + s[0][1] + s[0][2] + s[0][3]) * invB);
        atomicAdd(&out[1], (s[1][0] + s[1][1] + s[1][2] + s[1][3]) * (5.0f * invB));
        atomicAdd(&out[2], (s[2][0] + s[2][1] + s[2][2] + s[2][3]) * invB);
    }
}

extern "C" void kernel_launch(void* const* d_in, const int* in_sizes, int n_in,
                              void* d_out, int out_size, void* d_ws, size_t ws_size,
                              hipStream_t stream) {
    const float* pred   = (const float*)d_in[0];
    const float* target = (const float*)d_in[1];
    float* out = (float*)d_out;

    // d_out is poisoned before every launch -> zero the 3 accumulators (capture-safe).
    // d_ws is deliberately UNTOUCHED this round.
    hipMemsetAsync(d_out, 0, 3 * sizeof(float), stream);

    yolo_fused_kernel<<<GRID, BLOCK, 0, stream>>>(pred, target, out);
}

// Round 2
// 113.506 us; speedup vs baseline: 1.0964x; 1.0964x over previous
//
#include <hip/hip_runtime.h>

#define NCELLS (8192 * 7 * 7)      // 401408 cells of 30 floats each
#define BLOCK 128                  // 2 waves
#define CPB 128                    // cells per block
#define NBLOCKS (NCELLS / CPB)     // 3136 exactly
// LDS: 128 cells * 30 floats * 4 B * 2 arrays = 30720 B -> 5 blocks/CU = 10 waves/CU

__device__ __forceinline__ float sq(float x) { return x * x; }

__device__ __forceinline__ float iou_fn(const float* t, const float* p, float fi, float fj) {
    const float STEP = 1.0f / 7.0f;
    float w1 = t[2], h1 = t[3];
    float x1 = (t[0] + fj) * STEP, y1 = (t[1] + fi) * STEP;
    float a1 = fmaxf(x1 - w1 * 0.5f, 0.0f);
    float b1 = fmaxf(y1 - h1 * 0.5f, 0.0f);
    float w2 = p[2], h2 = p[3];
    float x2 = (p[0] + fj) * STEP, y2 = (p[1] + fi) * STEP;
    float a2 = fmaxf(x2 - w2 * 0.5f, 0.0f);
    float b2 = fmaxf(y2 - h2 * 0.5f, 0.0f);
    float iw = w1 + w2 - (fmaxf(a1 + w1, a2 + w2) - fminf(a1, a2));
    float ih = h1 + h2 - (fmaxf(b1 + h1, b2 + h2) - fminf(b1, b2));
    bool valid = (iw > 0.0f) && (ih > 0.0f);
    float inter = valid ? iw * ih : 0.0f;
    float uni = w1 * h1 + w2 * h2 - inter;
    return valid ? inter / uni : 0.0f;
}

// Pass 1: LDS-staged. Global loads are fully-coalesced float4 (1 KB/instr/wave,
// 4 cache lines) instead of R1's 120-B-stride float2 scatter (~60 lines/instr).
// Each block plain-stores 3 partials to its own d_ws slot -> no atomics, no memset.
__global__ __launch_bounds__(BLOCK) void yolo_part_kernel(
        const float* __restrict__ pred, const float* __restrict__ target,
        float4* __restrict__ partials) {
    __shared__ float s[2 * CPB * 30];          // [0,3840) pred chunk, [3840,7680) target
    const int tid = threadIdx.x;

    // ---- stage: 1920 float4 total (960 pred + 960 target), 15 rounds exactly ----
    const size_t blockBase = (size_t)blockIdx.x * (CPB * 30);   // floats, 16B-aligned
    const float4* gp = (const float4*)(pred + blockBase);
    const float4* gt = (const float4*)(target + blockBase);
    float4* ls = (float4*)s;
#pragma unroll
    for (int r = 0; r < 15; ++r) {
        int i = r * BLOCK + tid;               // 0..1919; i<960 -> pred (960 = 15 waves, no
        const float4* base = (i < 960) ? gp : (gt - 960);   //  intra-wave divergence)
        ls[i] = base[i];
    }
    __syncthreads();

    // ---- compute: one cell per thread, operands from LDS ----
    int c = blockIdx.x * CPB + tid;
    unsigned cell = (unsigned)c % 49u;
    float fi = (float)(cell / 7u);
    float fj = (float)(cell % 7u);

    const float* pl = s + tid * 30;            // stride-30: 4-way bank alias, negligible
    const float* tl = s + CPB * 30 + tid * 30;

    bool obj = tl[4] > 0.0f;                   // target[...,4] is exactly 1.0 or 0.0

    float iou1 = iou_fn(tl, pl, fi, fj);
    float iou2 = iou_fn(tl, pl + 5, fi, fj);
    bool choose1 = iou1 > iou2;
    float m1 = (obj && choose1 && (iou1 != 0.0f)) ? 1.0f : 0.0f;
    float m2 = (obj && !choose1 && (iou2 != 0.0f)) ? 1.0f : 0.0f;

    float obj_loss = m1 * sq(iou1 - pl[4]) + m2 * sq(iou2 - pl[9]);

    float xy = m1 * (sq(tl[0] - pl[0]) + sq(tl[1] - pl[1]))
             + m2 * (sq(tl[5] - pl[5]) + sq(tl[6] - pl[6]));

    float wh = m1 * (sq(sqrtf(tl[2]) - sqrtf(pl[2])) + sq(sqrtf(tl[3]) - sqrtf(pl[3])))
             + m2 * (sq(sqrtf(tl[7]) - sqrtf(pl[7])) + sq(sqrtf(tl[8]) - sqrtf(pl[8])));

    float noobj = 0.0f;
#pragma unroll
    for (int k = 0; k < 6; ++k) {
        int ci = 4 + 5 * k;                    // 4, 9, 14, 19, 24, 29
        noobj += sq(tl[ci] - pl[ci]);
    }
    if (obj) noobj = 0.0f;

    float clsum = 0.0f;
#pragma unroll
    for (int k = 10; k < 30; ++k) clsum += sq(pl[k] - tl[k]);
    if (!obj) clsum = 0.0f;

    float conf = obj_loss + 0.5f * noobj;
    float reg  = xy + wh;
    float cls  = clsum;

#pragma unroll
    for (int off = 32; off > 0; off >>= 1) {
        conf += __shfl_down(conf, off, 64);
        reg  += __shfl_down(reg,  off, 64);
        cls  += __shfl_down(cls,  off, 64);
    }

    __shared__ float sr[3][2];
    int lane = tid & 63;
    int wave = tid >> 6;
    if (lane == 0) { sr[0][wave] = conf; sr[1][wave] = reg; sr[2][wave] = cls; }
    __syncthreads();
    if (tid == 0) {
        const float invB = 1.0f / 8192.0f;     // sum-then-scale, matches ref order
        partials[blockIdx.x] = make_float4(
            (sr[0][0] + sr[0][1]) * invB,
            (sr[1][0] + sr[1][1]) * (5.0f * invB),
            (sr[2][0] + sr[2][1]) * invB,
            0.0f);
    }
}

// Pass 2: fold 3136 slots -> 3 outputs (plain stores overwrite poisoned d_out).
__global__ __launch_bounds__(256) void yolo_final_kernel(
        const float4* __restrict__ partials, float* __restrict__ out) {
    int tid = threadIdx.x;
    float a = 0.0f, b = 0.0f, d = 0.0f;
    for (int i = tid; i < NBLOCKS; i += 256) {
        float4 v = partials[i];
        a += v.x; b += v.y; d += v.z;
    }
#pragma unroll
    for (int off = 32; off > 0; off >>= 1) {
        a += __shfl_down(a, off, 64);
        b += __shfl_down(b, off, 64);
        d += __shfl_down(d, off, 64);
    }
    __shared__ float s[3][4];
    int lane = tid & 63;
    int wave = tid >> 6;
    if (lane == 0) { s[0][wave] = a; s[1][wave] = b; s[2][wave] = d; }
    __syncthreads();
    if (tid == 0) {
        out[0] = s[0][0] + s[0][1] + s[0][2] + s[0][3];
        out[1] = s[1][0] + s[1][1] + s[1][2] + s[1][3];
        out[2] = s[2][0] + s[2][1] + s[2][2] + s[2][3];
    }
}

extern "C" void kernel_launch(void* const* d_in, const int* in_sizes, int n_in,
                              void* d_out, int out_size, void* d_ws, size_t ws_size,
                              hipStream_t stream) {
    const float* pred   = (const float*)d_in[0];
    const float* target = (const float*)d_in[1];
    float* out = (float*)d_out;
    float4* partials = (float4*)d_ws;          // 3136 * 16 B = 50 KB; every slot written
                                               // before read -> no zero-init needed
    yolo_part_kernel<<<NBLOCKS, BLOCK, 0, stream>>>(pred, target, partials);
    yolo_final_kernel<<<1, 256, 0, stream>>>(partials, out);
}